// Round 7
// baseline (1179.470 us; speedup 1.0000x reference)
//
#include <hip/hip_runtime.h>
#include <hip/hip_bf16.h>

typedef unsigned short u16;
typedef __attribute__((ext_vector_type(4))) float f32x4;
typedef __attribute__((ext_vector_type(8))) short short8;
typedef __attribute__((ext_vector_type(8))) u16 us8;

// Geometry (fixed): B=64, N=256, DIM=2048, H=8, D=256; M=B*N=16384; qkvN=6144
// Per-head planes: [512][256][256]

__device__ __forceinline__ u16 f2bf(float f) {
  union { float f; unsigned u; } v; v.f = f;
  unsigned r = v.u + 0x7fffu + ((v.u >> 16) & 1u);   // RNE, finite inputs
  return (u16)(r >> 16);
}
__device__ __forceinline__ float bf2f(u16 h) {
  union { unsigned u; float f; } v; v.u = ((unsigned)h) << 16; return v.f;
}

__global__ void beacon_kernel(float* __restrict__ out, float val, int n) {
  int stride = gridDim.x * blockDim.x;
  for (int i = blockIdx.x * blockDim.x + threadIdx.x; i < n; i += stride)
    out[i] = val;
}

__global__ void split_kernel(const float* __restrict__ in, u16* __restrict__ hi,
                             u16* __restrict__ lo, int n4) {
  int stride = gridDim.x * blockDim.x;
  for (int i = blockIdx.x * blockDim.x + threadIdx.x; i < n4; i += stride) {
    f32x4 v = ((const f32x4*)in)[i];
    ushort4 h;
    h.x = f2bf(v[0]); h.y = f2bf(v[1]); h.z = f2bf(v[2]); h.w = f2bf(v[3]);
    ((ushort4*)hi)[i] = h;
    if (lo) {
      ushort4 l;
      l.x = f2bf(v[0] - bf2f(h.x)); l.y = f2bf(v[1] - bf2f(h.y));
      l.z = f2bf(v[2] - bf2f(h.z)); l.w = f2bf(v[3] - bf2f(h.w));
      ((ushort4*)lo)[i] = l;
    }
  }
}

#define SCHED0 __builtin_amdgcn_sched_barrier(0)
#define LGKM0 do { asm volatile("s_waitcnt lgkmcnt(0)" ::: "memory"); SCHED0; } while (0)
#define VM8 do { asm volatile("s_waitcnt vmcnt(8)" ::: "memory"); } while (0)
#define VM4 do { asm volatile("s_waitcnt vmcnt(4)" ::: "memory"); } while (0)
#define VM0 do { asm volatile("s_waitcnt vmcnt(0)" ::: "memory"); } while (0)
#define BAR __builtin_amdgcn_s_barrier()

// ====== 256x256 bf16 NT GEMM, BK=32, 4-deep LDS ring, counted vmcnt ======
// C[M,N] = A[M,K']*B[N,K']^T; K' = up to 2 concatenated segments.
// 512 thr = 8 waves (2M x 4N), per-wave out 128x64, acc[8][4].
// Ring invariant: tile t's 4 loads/thread are the OLDEST of <=12 outstanding
// (t, t+1, t+2 sets) => vmcnt(8) retires them; single barrier per tile; each
// wave's lgkmcnt(0) in tile u finishes its reads of buf[u&3] before the next
// barrier, so stage(t+3) overwriting buf[(t-1)&3] is safe.
// LDS slot swizzle (4 slots of 16B per 64B row): read slot (g+row)&3; source
// col pre-swizzled with the inverse (rule 21).
// EPI 0: qkv->q,k scatter (hi+lo); EPI 1: qkv->v plane; EPI 2: proj out+bias.
template<int EPI>
__global__ __launch_bounds__(512, 2)
void gemm256(const u16* __restrict__ A0, const u16* __restrict__ A1,
             const u16* __restrict__ B0, const u16* __restrict__ B1,
             int ldA, int ldB, int ntiles, int segShift, int gridMx,
             u16* __restrict__ qh, u16* __restrict__ ql,
             u16* __restrict__ kh, u16* __restrict__ kl,
             u16* __restrict__ vv,
             float* __restrict__ fout, const float* __restrict__ bias) {
  extern __shared__ __align__(16) u16 lds[];   // 4 bufs x (A[256][32]+B[256][32]) = 128 KiB

  const int tid = threadIdx.x;
  const int w = tid >> 6, lane = tid & 63;
  const int wr = w >> 2, wcn = w & 3;          // 2M x 4N waves
  const int l15 = lane & 15, g = lane >> 4;
  const int rsl = (g + l15) & 3;               // read-side physical slot
  const int scol = ((((tid & 3) - ((tid >> 2) & 3)) & 3) << 3);  // inverse pre-swz

  // XCD-bijective swizzle (gridDim.x % 8 == 0), m-fastest per XCD
  int bid = blockIdx.x, cpx = gridDim.x >> 3;
  int swz = (bid & 7) * cpx + (bid >> 3);
  int m0 = (swz % gridMx) << 8;
  int n0 = (swz / gridMx) << 8;

  const u16* As[2] = {A0, A1};
  const u16* Bs[2] = {B0, B1};
  const int kmask = (1 << segShift) - 1;

  f32x4 acc[8][4] = {};
  short8 af[8], bfr[4];

  // stage tile -> ring buffer db: per thread 2 A-strips + 2 B-strips (4 loads).
  // LDS dest linear (tid*16B within strip); global source col pre-swizzled.
  auto stage = [&](int db, const u16* Ab, const u16* Bb, int k0) {
    #pragma unroll
    for (int s = 0; s < 2; ++s) {
      const u16* srcA = Ab + (size_t)(m0 + s * 128 + (tid >> 2)) * ldA + k0 + scol;
      u16* dstA = lds + db * 16384 + s * 4096 + tid * 8;
      __builtin_amdgcn_global_load_lds(
          (const __attribute__((address_space(1))) unsigned*)srcA,
          (__attribute__((address_space(3))) unsigned*)dstA, 16, 0, 0);
      const u16* srcB = Bb + (size_t)(n0 + s * 128 + (tid >> 2)) * ldB + k0 + scol;
      u16* dstB = lds + db * 16384 + 8192 + s * 4096 + tid * 8;
      __builtin_amdgcn_global_load_lds(
          (const __attribute__((address_space(1))) unsigned*)srcB,
          (__attribute__((address_space(3))) unsigned*)dstB, 16, 0, 0);
    }
  };
  auto readAB = [&](int db) {   // 8 + 4 ds_read_b128
    const u16* base = lds + db * 16384;
    #pragma unroll
    for (int i = 0; i < 8; ++i) {
      int row = wr * 128 + i * 16 + l15;
      af[i] = *(const short8*)(base + row * 32 + rsl * 8);
    }
    #pragma unroll
    for (int j = 0; j < 4; ++j) {
      int row = wcn * 64 + j * 16 + l15;
      bfr[j] = *(const short8*)(base + 8192 + row * 32 + rsl * 8);
    }
  };

#define MMA_ALL                                                                \
  __builtin_amdgcn_s_setprio(1);                                               \
  _Pragma("unroll") for (int i = 0; i < 8; ++i)                                \
    _Pragma("unroll") for (int j = 0; j < 4; ++j)                              \
      acc[i][j] = __builtin_amdgcn_mfma_f32_16x16x32_bf16(                     \
          af[i], bfr[j], acc[i][j], 0, 0, 0);                                  \
  __builtin_amdgcn_s_setprio(0)

  const int T = ntiles;   // T >= 4 always here (min 64)
  // prologue: stage tiles 0,1,2 (12 loads in flight)
  #pragma unroll
  for (int p = 0; p < 3; ++p)
    stage(p, As[p >> segShift], Bs[p >> segShift], (p & kmask) << 5);

  for (int t = 0; t < T - 3; ++t) {
    VM8; BAR; SCHED0;
    readAB(t & 3);
    int t3 = t + 3;
    stage(t3 & 3, As[t3 >> segShift], Bs[t3 >> segShift], (t3 & kmask) << 5);
    LGKM0;
    MMA_ALL;
  }
  VM8; BAR; SCHED0; readAB((T - 3) & 3); LGKM0; MMA_ALL;
  VM4; BAR; SCHED0; readAB((T - 2) & 3); LGKM0; MMA_ALL;
  VM0; BAR; SCHED0; readAB((T - 1) & 3); LGKM0; MMA_ALL;
#undef MMA_ALL

  // epilogue: C/D layout (m89/m91): col = lane&15, row = (lane>>4)*4 + reg
  #pragma unroll
  for (int i = 0; i < 8; ++i)
    #pragma unroll
    for (int j = 0; j < 4; ++j)
      #pragma unroll
      for (int rr = 0; rr < 4; ++rr) {
        int gm = m0 + wr * 128 + i * 16 + g * 4 + rr;
        int gn = n0 + wcn * 64 + j * 16 + l15;
        float val = acc[i][j][rr];
        if constexpr (EPI == 0) {
          int b = gm >> 8, tok = gm & 255;
          int sel = gn >> 11, head = (gn >> 8) & 7, col = gn & 255;
          size_t addr = (((size_t)b * 8 + head) * 256 + tok) * 256 + col;
          u16 h = f2bf(val), lo = f2bf(val - bf2f(h));
          if (sel == 0) { qh[addr] = h; ql[addr] = lo; }
          else          { kh[addr] = h; kl[addr] = lo; }
        } else if constexpr (EPI == 1) {
          int b = gm >> 8, tok = gm & 255;
          int head = (gn >> 8) & 7, col = gn & 255;
          size_t addr = (((size_t)b * 8 + head) * 256 + tok) * 256 + col;
          vv[addr] = f2bf(val);
        } else {
          fout[(size_t)gm * 2048 + gn] = val + bias[gn];
        }
      }
}

// ============ plain bf16 NT GEMM (m97 structure, HW-validated) — G2/G3 ============
template<int EPI, int SWZ>
__global__ __launch_bounds__(256)
void gemm_nt(const u16* __restrict__ A0, const u16* __restrict__ A1, const u16* __restrict__ A2,
             const u16* __restrict__ B0, const u16* __restrict__ B1, const u16* __restrict__ B2,
             float* __restrict__ sout, u16* __restrict__ aout,
             int ksteps, int segShift, int plane_base) {
  __shared__ __align__(16) u16 lds[8192];   // 2 slots x [128][32] bf16
  u16* sA = lds;
  u16* sB = lds + 4096;

  const int tid = threadIdx.x;
  const int wave = tid >> 6, lane = tid & 63;
  const int wr = wave >> 1, wc = wave & 1;
  const int l15 = lane & 15, l16 = lane >> 4;
  const int sxor = (l15 >> 1) & 3;

  size_t zoffA = 0, zoffB = 0;
  if constexpr (EPI == 2) {
    size_t gz = (size_t)(plane_base + blockIdx.z) * 65536;
    zoffA = gz; zoffB = gz;
  }
  if constexpr (EPI == 3) {
    zoffA = (size_t)blockIdx.z * 65536;
    zoffB = (size_t)(plane_base + blockIdx.z) * 65536;
  }
  const u16* As[3] = {A0 + zoffA, A1 + zoffA, A2 + zoffA};
  const u16* Bs[3] = {B0 + zoffB, B1 + zoffB, B2 + zoffB};

  const int m0 = blockIdx.x << 7;
  const int n0 = blockIdx.y << 7;
  const int kmask = (1 << segShift) - 1;

  f32x4 acc[4][4] = {};

  auto stage = [&](const u16* gp, int ld, u16* slot, int row0, int k0) {
    int scol = ((lane & 3) ^ ((lane >> 3) & 3)) * 8;
    #pragma unroll
    for (int c = 0; c < 2; ++c) {
      int chunk = wave + c * 4;
      int r = chunk * 16 + (lane >> 2);
      const u16* src = gp + (size_t)(row0 + r) * ld + (k0 + scol);
      __builtin_amdgcn_global_load_lds(
          (const __attribute__((address_space(1))) unsigned*)src,
          (__attribute__((address_space(3))) unsigned*)(slot + chunk * 512), 16, 0, 0);
    }
  };

  for (int ks = 0; ks < ksteps; ++ks) {
    int seg = ks >> segShift;
    int k0 = (ks & kmask) * 32;
    stage(As[seg], 256, sA, m0, k0);
    stage(Bs[seg], 256, sB, n0, k0);
    __syncthreads();

    short8 a[4], b[4];
    #pragma unroll
    for (int i = 0; i < 4; ++i) {
      int ra = (wr * 64 + i * 16 + l15) * 4 + (l16 ^ sxor);
      int rb = (wc * 64 + i * 16 + l15) * 4 + (l16 ^ sxor);
      a[i] = ((const short8*)sA)[ra];
      b[i] = ((const short8*)sB)[rb];
    }
    #pragma unroll
    for (int i = 0; i < 4; ++i)
      #pragma unroll
      for (int j = 0; j < 4; ++j)
        acc[i][j] = __builtin_amdgcn_mfma_f32_16x16x32_bf16(a[i], b[j], acc[i][j], 0, 0, 0);
    __syncthreads();
  }

  #pragma unroll
  for (int i = 0; i < 4; ++i)
    #pragma unroll
    for (int j = 0; j < 4; ++j)
      #pragma unroll
      for (int r = 0; r < 4; ++r) {
        int gm = m0 + wr * 64 + i * 16 + l16 * 4 + r;
        int gn = n0 + wc * 64 + j * 16 + l15;
        float val = acc[i][j][r];
        if constexpr (EPI == 2) {
          sout[(size_t)blockIdx.z * 65536 + (size_t)gm * 256 + gn] = val;
        } else {
          int gp = plane_base + blockIdx.z;
          size_t row = (size_t)(gp >> 3) * 256 + gm;
          size_t col = (size_t)(gp & 7) * 256 + gn;
          aout[row * 2048 + col] = f2bf(val);
        }
      }
}

// ---------- per-head 256x256 in-place transpose (k_hi, k_lo, v) ----------
__global__ void transpose_inplace(u16* __restrict__ kh, u16* __restrict__ kl,
                                  u16* __restrict__ v) {
  __shared__ u16 ta[64][66], tb[64][66];
  u16* base = (blockIdx.z == 0) ? kh : (blockIdx.z == 1) ? kl : v;
  u16* pl = base + (size_t)blockIdx.y * 65536;
  const int RA[10] = {0,1,2,3, 0,0,0,1,1,2};
  const int CA[10] = {0,1,2,3, 1,2,3,2,3,3};
  int p = blockIdx.x;
  int R = RA[p], C = CA[p];
  bool diag = (R == C);
  int tid = threadIdx.x;
  int r = tid >> 2, c0 = (tid & 3) * 16;

  const us8* sa = (const us8*)(pl + (size_t)(R * 64 + r) * 256 + C * 64 + c0);
  us8 a0 = sa[0], a1 = sa[1];
  #pragma unroll
  for (int s = 0; s < 8; ++s) { ta[r][c0 + s] = a0[s]; ta[r][c0 + 8 + s] = a1[s]; }
  if (!diag) {
    const us8* sb = (const us8*)(pl + (size_t)(C * 64 + r) * 256 + R * 64 + c0);
    us8 b0 = sb[0], b1 = sb[1];
    #pragma unroll
    for (int s = 0; s < 8; ++s) { tb[r][c0 + s] = b0[s]; tb[r][c0 + 8 + s] = b1[s]; }
  }
  __syncthreads();
  us8 o0, o1;
  #pragma unroll
  for (int s = 0; s < 8; ++s) { o0[s] = ta[c0 + s][r]; o1[s] = ta[c0 + 8 + s][r]; }
  us8* da = (us8*)(pl + (size_t)(C * 64 + r) * 256 + R * 64 + c0);
  da[0] = o0; da[1] = o1;
  if (!diag) {
    us8 p0, p1;
    #pragma unroll
    for (int s = 0; s < 8; ++s) { p0[s] = tb[c0 + s][r]; p1[s] = tb[c0 + 8 + s][r]; }
    us8* db = (us8*)(pl + (size_t)(R * 64 + r) * 256 + C * 64 + c0);
    db[0] = p0; db[1] = p1;
  }
}

// ---------- row softmax over 256 fp32 -> bf16 P; one wave per row ----------
__global__ void softmax_kernel(const float* __restrict__ S, u16* __restrict__ P) {
  int row = blockIdx.x * 4 + (threadIdx.x >> 6);
  int lane = threadIdx.x & 63;
  f32x4 v = ((const f32x4*)(S + (size_t)row * 256))[lane];
  float mx = fmaxf(fmaxf(v[0], v[1]), fmaxf(v[2], v[3]));
  #pragma unroll
  for (int o = 32; o > 0; o >>= 1) mx = fmaxf(mx, __shfl_xor(mx, o));
  float e0 = __expf(v[0] - mx), e1 = __expf(v[1] - mx);
  float e2 = __expf(v[2] - mx), e3 = __expf(v[3] - mx);
  float sum = e0 + e1 + e2 + e3;
  #pragma unroll
  for (int o = 32; o > 0; o >>= 1) sum += __shfl_xor(sum, o);
  float inv = 1.0f / sum;
  ushort4 p;
  p.x = f2bf(e0 * inv); p.y = f2bf(e1 * inv); p.z = f2bf(e2 * inv); p.w = f2bf(e3 * inv);
  ((ushort4*)(P + (size_t)row * 256))[lane] = p;
}

extern "C" void kernel_launch(void* const* d_in, const int* in_sizes, int n_in,
                              void* d_out, int out_size, void* d_ws, size_t ws_size,
                              hipStream_t stream) {
  const float* x  = (const float*)d_in[0];   // [16384, 2048]
  const float* wq = (const float*)d_in[1];   // [6144, 2048]
  const float* wp = (const float*)d_in[2];   // [2048, 2048]
  const float* bp = (const float*)d_in[3];   // [2048]
  float* out = (float*)d_out;
  char* ws = (char*)d_ws;

  const size_t MB = 1ull << 20;
  const size_t NEED = 432 * MB;
  if (ws_size < NEED) {
    beacon_kernel<<<2048, 256, 0, stream>>>(out, (float)(ws_size >> 20), 16384 * 2048);
    return;
  }

  // persistent per-head tensors [0, 320 MiB)
  u16* q_hi = (u16*)(ws);
  u16* q_lo = (u16*)(ws + 64 * MB);
  u16* k_hi = (u16*)(ws + 128 * MB);
  u16* k_lo = (u16*)(ws + 192 * MB);
  u16* vbuf = (u16*)(ws + 256 * MB);
  // G1 phase window [320, 432 MiB)
  u16* x_hi = (u16*)(ws + 320 * MB);   // 64 MiB
  u16* w_hi = (u16*)(ws + 384 * MB);   // 24 MiB
  u16* w_lo = (u16*)(ws + 408 * MB);   // 24 MiB
  // attention phase window (x, w dead)
  float* S  = (float*)(ws + 320 * MB); // 32 MiB
  u16* Pm   = (u16*)(ws + 352 * MB);   // 16 MiB
  u16* attn = (u16*)(ws + 368 * MB);   // 64 MiB (lives into proj)
  u16* wpb  = (u16*)(ws + 320 * MB);   //  8 MiB (over dead S)

  // prep: x -> hi only; w_qkv -> hi+lo
  split_kernel<<<8192, 256, 0, stream>>>(x,  x_hi, nullptr, 16384 * 2048 / 4);
  split_kernel<<<4096, 256, 0, stream>>>(wq, w_hi, w_lo, 6144 * 2048 / 4);

  // G1 qk: q,k = x_hi @ (w_hi | w_lo)^T  (2 K-segments of 64 BK=32 tiles)
  gemm256<0><<<1024, 512, 131072, stream>>>(
      x_hi, x_hi, w_hi, w_lo, 2048, 2048, 128, 6, 64,
      q_hi, q_lo, k_hi, k_lo, nullptr, nullptr, nullptr);
  // G1 v: v = x_hi @ wv_hi^T  (1 segment, 64 tiles)
  const u16* wv = w_hi + (size_t)4096 * 2048;
  gemm256<1><<<512, 512, 131072, stream>>>(
      x_hi, x_hi, wv, wv, 2048, 2048, 64, 6, 64,
      nullptr, nullptr, nullptr, nullptr, vbuf, nullptr, nullptr);

  // in-place per-head transpose of k (hi,lo) and v
  transpose_inplace<<<dim3(10, 512, 3), 256, 0, stream>>>(k_hi, k_lo, vbuf);

  // attention in 4 groups of 128 planes
  for (int gp = 0; gp < 4; ++gp) {
    int pb = gp * 128;
    // S^T = kT*q^T, 3-term compensation as 3 K-segments of 256
    gemm_nt<2, 0><<<dim3(2, 2, 128), 256, 0, stream>>>(
        k_hi, k_hi, k_lo, q_hi, q_lo, q_hi,
        S, nullptr, 24, 3, pb);
    softmax_kernel<<<8192, 256, 0, stream>>>(S, Pm);
    // PV: attn = P @ vT^T
    gemm_nt<3, 0><<<dim3(2, 2, 128), 256, 0, stream>>>(
        Pm, Pm, Pm, vbuf, vbuf, vbuf,
        nullptr, attn, 8, 3, pb);
  }

  // proj: out = attn @ wp^T + bias  (64 tiles)
  split_kernel<<<2048, 256, 0, stream>>>(wp, wpb, nullptr, 2048 * 2048 / 4);
  gemm256<2><<<512, 512, 131072, stream>>>(
      attn, attn, wpb, wpb, 2048, 2048, 64, 6, 64,
      nullptr, nullptr, nullptr, nullptr, nullptr, out, bp);
}

// Round 8
// 1145.531 us; speedup vs baseline: 1.0296x; 1.0296x over previous
//
#include <hip/hip_runtime.h>
#include <hip/hip_bf16.h>

typedef unsigned short u16;
typedef __attribute__((ext_vector_type(4))) float f32x4;
typedef __attribute__((ext_vector_type(8))) short short8;
typedef __attribute__((ext_vector_type(8))) u16 us8;

// Geometry (fixed): B=64, N=256, DIM=2048, H=8, D=256; M=B*N=16384; qkvN=6144

__device__ __forceinline__ u16 f2bf(float f) {
  union { float f; unsigned u; } v; v.f = f;
  unsigned r = v.u + 0x7fffu + ((v.u >> 16) & 1u);   // RNE, finite inputs
  return (u16)(r >> 16);
}
__device__ __forceinline__ float bf2f(u16 h) {
  union { unsigned u; float f; } v; v.u = ((unsigned)h) << 16; return v.f;
}

__global__ void beacon_kernel(float* __restrict__ out, float val, int n) {
  int stride = gridDim.x * blockDim.x;
  for (int i = blockIdx.x * blockDim.x + threadIdx.x; i < n; i += stride)
    out[i] = val;
}

__global__ void split_kernel(const float* __restrict__ in, u16* __restrict__ hi,
                             u16* __restrict__ lo, int n4) {
  int stride = gridDim.x * blockDim.x;
  for (int i = blockIdx.x * blockDim.x + threadIdx.x; i < n4; i += stride) {
    f32x4 v = ((const f32x4*)in)[i];
    ushort4 h;
    h.x = f2bf(v[0]); h.y = f2bf(v[1]); h.z = f2bf(v[2]); h.w = f2bf(v[3]);
    ((ushort4*)hi)[i] = h;
    if (lo) {
      ushort4 l;
      l.x = f2bf(v[0] - bf2f(h.x)); l.y = f2bf(v[1] - bf2f(h.y));
      l.z = f2bf(v[2] - bf2f(h.z)); l.w = f2bf(v[3] - bf2f(h.w));
      ((ushort4*)lo)[i] = l;
    }
  }
}

#define SCHED0 __builtin_amdgcn_sched_barrier(0)
#define LGKM0 do { asm volatile("s_waitcnt lgkmcnt(0)" ::: "memory"); SCHED0; } while (0)
#define VM6 do { asm volatile("s_waitcnt vmcnt(6)" ::: "memory"); } while (0)
#define VM0 do { asm volatile("s_waitcnt vmcnt(0)" ::: "memory"); } while (0)
#define BAR __builtin_amdgcn_s_barrier()

// ====== 256x256 bf16 NT GEMM — 8-phase half-tile ring, counted vmcnt(6) ======
// C[M,N] = A[M,K']*B[N,K']^T; K' = up to 2 concatenated segments; BK=64.
// 512 thr = 8 waves; per phase ALL waves compute one block-quadrant (MH,NH)
// (128x128 x K=64); wave w -> (qr=w>>2)*64 rows, (qc=w&3)*32 cols in-quadrant.
// LDS: 8 half-slots (A0,A1,B0,B1 x tile-parity) x 16KB = 128 KiB.
// Ring: each phase stages ONE half (2 loads/thread) into the slot freed by the
// previous phase; vmcnt(6) at P4/P8 confirms (outstanding 7 halves - newest 3)
// = exactly the 4 halves the next 4 phases read.  Slot swizzle: phys slot =
// (k*4+g) ^ (row&7) on read; source col pre-swizzled to match (rule 21,
// bit-exact-validated in rounds 5/6).
// EPI 0: qkv->q,k scatter (hi+lo); EPI 1: qkv->v plane; EPI 2: proj out+bias.
template<int EPI>
__global__ __launch_bounds__(512, 2)
void gemm256(const u16* __restrict__ A0p, const u16* __restrict__ A1p,
             const u16* __restrict__ B0p, const u16* __restrict__ B1p,
             int ldA, int ldB, int ntiles, int segShift, int gridMx,
             u16* __restrict__ qh, u16* __restrict__ ql,
             u16* __restrict__ kh, u16* __restrict__ kl,
             u16* __restrict__ vv,
             float* __restrict__ fout, const float* __restrict__ bias) {
  extern __shared__ __align__(16) u16 lds[];   // 8 x 16KB half-slots

  const int tid = threadIdx.x;
  const int w = tid >> 6, lane = tid & 63;
  const int qr = w >> 2, qc = w & 3;           // wave pos inside a 128x128 quadrant
  const int l15 = lane & 15, g = lane >> 4;
  const int rsw = l15 & 7;
  const int scol = (((tid & 7) ^ ((tid >> 3) & 7)) << 3);   // staging pre-swizzle

  // XCD-bijective swizzle (gridDim.x % 8 == 0), m-fastest per XCD
  int bid = blockIdx.x, cpx = gridDim.x >> 3;
  int swz = (bid & 7) * cpx + (bid >> 3);
  int m0 = (swz % gridMx) << 8;
  int n0 = (swz / gridMx) << 8;

  const u16* As[2] = {A0p, A1p};
  const u16* Bs[2] = {B0p, B1p};
  const int kmask = (1 << segShift) - 1;

  f32x4 acc[8][4] = {};
  short8 aR[8], bR[4];

  // stage half h (128 rows x 64 cols) of A or B for tile t into its slot.
  // slot id: A-half h -> h*2 + (t&1); B-half h -> (2+h)*2 + (t&1).
  auto stA = [&](int t, int h) {
    const u16* bp = As[t >> segShift];
    int k0 = (t & kmask) << 6;
    u16* dst0 = lds + (h * 2 + (t & 1)) * 8192 + tid * 8;
    #pragma unroll
    for (int L = 0; L < 2; ++L) {
      const u16* src = bp + (size_t)(m0 + h * 128 + L * 64 + (tid >> 3)) * ldA + k0 + scol;
      __builtin_amdgcn_global_load_lds(
          (const __attribute__((address_space(1))) unsigned*)src,
          (__attribute__((address_space(3))) unsigned*)(dst0 + L * 4096), 16, 0, 0);
    }
  };
  auto stB = [&](int t, int h) {
    const u16* bp = Bs[t >> segShift];
    int k0 = (t & kmask) << 6;
    u16* dst0 = lds + ((2 + h) * 2 + (t & 1)) * 8192 + tid * 8;
    #pragma unroll
    for (int L = 0; L < 2; ++L) {
      const u16* src = bp + (size_t)(n0 + h * 128 + L * 64 + (tid >> 3)) * ldB + k0 + scol;
      __builtin_amdgcn_global_load_lds(
          (const __attribute__((address_space(1))) unsigned*)src,
          (__attribute__((address_space(3))) unsigned*)(dst0 + L * 4096), 16, 0, 0);
    }
  };
  auto readA = [&](int par, int MH) {   // 8 x ds_read_b128
    const u16* base = lds + (MH * 2 + par) * 8192;
    #pragma unroll
    for (int fm = 0; fm < 4; ++fm) {
      int lrow = qr * 64 + fm * 16 + l15;
      #pragma unroll
      for (int k = 0; k < 2; ++k) {
        int sl = (k * 4 + g) ^ rsw;
        aR[fm * 2 + k] = *(const short8*)(base + lrow * 64 + sl * 8);
      }
    }
  };
  auto readB = [&](int par, int NH) {   // 4 x ds_read_b128
    const u16* base = lds + ((2 + NH) * 2 + par) * 8192;
    #pragma unroll
    for (int fn = 0; fn < 2; ++fn) {
      int lrow = qc * 32 + fn * 16 + l15;
      #pragma unroll
      for (int k = 0; k < 2; ++k) {
        int sl = (k * 4 + g) ^ rsw;
        bR[fn * 2 + k] = *(const short8*)(base + lrow * 64 + sl * 8);
      }
    }
  };

#define MMA_PH(MH, NH)                                                         \
  __builtin_amdgcn_s_setprio(1);                                               \
  _Pragma("unroll") for (int fm = 0; fm < 4; ++fm)                             \
    _Pragma("unroll") for (int fn = 0; fn < 2; ++fn)                           \
      _Pragma("unroll") for (int k = 0; k < 2; ++k)                            \
        acc[(MH) * 4 + fm][(NH) * 2 + fn] =                                    \
            __builtin_amdgcn_mfma_f32_16x16x32_bf16(                           \
                aR[fm * 2 + k], bR[fn * 2 + k],                                \
                acc[(MH) * 4 + fm][(NH) * 2 + fn], 0, 0, 0);                   \
  __builtin_amdgcn_s_setprio(0)

  const int T = ntiles;   // even, >= 4
  // prologue: tile0 all 4 halves; tile1 A0,B1,A1 (B0(t1) staged at iter0-P1)
  stA(0, 0); stB(0, 0); stB(0, 1); stA(0, 1);
  stA(1, 0); stB(1, 1); stA(1, 1);
  VM6; BAR; SCHED0;    // 14 outstanding -> confirms tile0's 8; tile1's 6 in flight

  #pragma unroll 1
  for (int i = 0; i < T / 2; ++i) {
    const int ta = 2 * i, tb = ta + 1;       // par(ta)=0, par(tb)=1
    const bool last = (i == T / 2 - 1);
    // P1: quad(0,0) of ta; stage B0(tb) [slot B0[1] freed at prev P8]
    readA(0, 0); readB(0, 0);
    stB(tb, 0);
    BAR; LGKM0; MMA_PH(0, 0);
    BAR; SCHED0;
    // P2: quad(0,1); A kept; stage A0(ta+2) [A0[0] freed at P1]
    readB(0, 1);
    if (!last) stA(ta + 2, 0);
    BAR; LGKM0; MMA_PH(0, 1);
    BAR; SCHED0;
    // P3: quad(1,1); B1 kept; stage B1(ta+2) [B1[0] freed at P2]
    readA(0, 1);
    if (!last) stB(ta + 2, 1);
    BAR; LGKM0; MMA_PH(1, 1);
    BAR; SCHED0;
    // P4: quad(1,0); re-read B0; stage A1(ta+2) [A1[0] freed at P3]; wait
    readB(0, 0);
    if (!last) stA(ta + 2, 1);
    BAR; LGKM0; MMA_PH(1, 0);
    if (last) { VM0; } else { VM6; }   // confirms tile tb complete
    BAR; SCHED0;
    // P5: quad(0,0) of tb; stage B0(ta+2) [B0[0] freed at P4]
    readA(1, 0); readB(1, 0);
    if (!last) stB(ta + 2, 0);
    BAR; LGKM0; MMA_PH(0, 0);
    BAR; SCHED0;
    // P6: quad(0,1); stage A0(tb+2) [A0[1] freed at P5]
    readB(1, 1);
    if (!last) stA(tb + 2, 0);
    BAR; LGKM0; MMA_PH(0, 1);
    BAR; SCHED0;
    // P7: quad(1,1); stage B1(tb+2) [B1[1] freed at P6]
    readA(1, 1);
    if (!last) stB(tb + 2, 1);
    BAR; LGKM0; MMA_PH(1, 1);
    BAR; SCHED0;
    // P8: quad(1,0); re-read B0; stage A1(tb+2) [A1[1] freed at P7]; wait
    readB(1, 0);
    if (!last) stA(tb + 2, 1);
    BAR; LGKM0; MMA_PH(1, 0);
    if (!last) { VM6; }                // confirms tile ta+2 complete
    BAR; SCHED0;
  }
#undef MMA_PH

  // epilogue: C/D layout (m89/m91): col = lane&15, row = (lane>>4)*4 + reg
  #pragma unroll
  for (int i = 0; i < 8; ++i)
    #pragma unroll
    for (int j = 0; j < 4; ++j)
      #pragma unroll
      for (int rr = 0; rr < 4; ++rr) {
        int gm = m0 + (i >> 2) * 128 + qr * 64 + (i & 3) * 16 + g * 4 + rr;
        int gn = n0 + (j >> 1) * 128 + qc * 32 + (j & 1) * 16 + l15;
        float val = acc[i][j][rr];
        if constexpr (EPI == 0) {
          int b = gm >> 8, tok = gm & 255;
          int sel = gn >> 11, head = (gn >> 8) & 7, col = gn & 255;
          size_t addr = (((size_t)b * 8 + head) * 256 + tok) * 256 + col;
          u16 h = f2bf(val), lo = f2bf(val - bf2f(h));
          if (sel == 0) { qh[addr] = h; ql[addr] = lo; }
          else          { kh[addr] = h; kl[addr] = lo; }
        } else if constexpr (EPI == 1) {
          int b = gm >> 8, tok = gm & 255;
          int head = (gn >> 8) & 7, col = gn & 255;
          size_t addr = (((size_t)b * 8 + head) * 256 + tok) * 256 + col;
          vv[addr] = f2bf(val);
        } else {
          fout[(size_t)gm * 2048 + gn] = val + bias[gn];
        }
      }
}

// ============ plain bf16 NT GEMM (m97 structure, HW-validated) — G2/G3 ============
template<int EPI, int SWZ>
__global__ __launch_bounds__(256)
void gemm_nt(const u16* __restrict__ A0, const u16* __restrict__ A1, const u16* __restrict__ A2,
             const u16* __restrict__ B0, const u16* __restrict__ B1, const u16* __restrict__ B2,
             float* __restrict__ sout, u16* __restrict__ aout,
             int ksteps, int segShift, int plane_base) {
  __shared__ __align__(16) u16 lds[8192];
  u16* sA = lds;
  u16* sB = lds + 4096;

  const int tid = threadIdx.x;
  const int wave = tid >> 6, lane = tid & 63;
  const int wr = wave >> 1, wc = wave & 1;
  const int l15 = lane & 15, l16 = lane >> 4;
  const int sxor = (l15 >> 1) & 3;

  size_t zoffA = 0, zoffB = 0;
  if constexpr (EPI == 2) {
    size_t gz = (size_t)(plane_base + blockIdx.z) * 65536;
    zoffA = gz; zoffB = gz;
  }
  if constexpr (EPI == 3) {
    zoffA = (size_t)blockIdx.z * 65536;
    zoffB = (size_t)(plane_base + blockIdx.z) * 65536;
  }
  const u16* As[3] = {A0 + zoffA, A1 + zoffA, A2 + zoffA};
  const u16* Bs[3] = {B0 + zoffB, B1 + zoffB, B2 + zoffB};

  const int m0 = blockIdx.x << 7;
  const int n0 = blockIdx.y << 7;
  const int kmask = (1 << segShift) - 1;

  f32x4 acc[4][4] = {};

  auto stage = [&](const u16* gp, u16* slot, int row0, int k0) {
    int scol = ((lane & 3) ^ ((lane >> 3) & 3)) * 8;
    #pragma unroll
    for (int c = 0; c < 2; ++c) {
      int chunk = wave + c * 4;
      int r = chunk * 16 + (lane >> 2);
      const u16* src = gp + (size_t)(row0 + r) * 256 + (k0 + scol);
      __builtin_amdgcn_global_load_lds(
          (const __attribute__((address_space(1))) unsigned*)src,
          (__attribute__((address_space(3))) unsigned*)(slot + chunk * 512), 16, 0, 0);
    }
  };

  for (int ks = 0; ks < ksteps; ++ks) {
    int seg = ks >> segShift;
    int k0 = (ks & kmask) * 32;
    stage(As[seg], sA, m0, k0);
    stage(Bs[seg], sB, n0, k0);
    __syncthreads();

    short8 a[4], b[4];
    #pragma unroll
    for (int i = 0; i < 4; ++i) {
      int ra = (wr * 64 + i * 16 + l15) * 4 + (l16 ^ sxor);
      int rb = (wc * 64 + i * 16 + l15) * 4 + (l16 ^ sxor);
      a[i] = ((const short8*)sA)[ra];
      b[i] = ((const short8*)sB)[rb];
    }
    #pragma unroll
    for (int i = 0; i < 4; ++i)
      #pragma unroll
      for (int j = 0; j < 4; ++j)
        acc[i][j] = __builtin_amdgcn_mfma_f32_16x16x32_bf16(a[i], b[j], acc[i][j], 0, 0, 0);
    __syncthreads();
  }

  #pragma unroll
  for (int i = 0; i < 4; ++i)
    #pragma unroll
    for (int j = 0; j < 4; ++j)
      #pragma unroll
      for (int r = 0; r < 4; ++r) {
        int gm = m0 + wr * 64 + i * 16 + l16 * 4 + r;
        int gn = n0 + wc * 64 + j * 16 + l15;
        float val = acc[i][j][r];
        if constexpr (EPI == 2) {
          sout[(size_t)blockIdx.z * 65536 + (size_t)gm * 256 + gn] = val;
        } else {
          int gp = plane_base + blockIdx.z;
          size_t row = (size_t)(gp >> 3) * 256 + gm;
          size_t col = (size_t)(gp & 7) * 256 + gn;
          aout[row * 2048 + col] = f2bf(val);
        }
      }
}

// ---------- per-head 256x256 in-place transpose (k_hi, k_lo, v) ----------
__global__ void transpose_inplace(u16* __restrict__ kh, u16* __restrict__ kl,
                                  u16* __restrict__ v) {
  __shared__ u16 ta[64][66], tb[64][66];
  u16* base = (blockIdx.z == 0) ? kh : (blockIdx.z == 1) ? kl : v;
  u16* pl = base + (size_t)blockIdx.y * 65536;
  const int RA[10] = {0,1,2,3, 0,0,0,1,1,2};
  const int CA[10] = {0,1,2,3, 1,2,3,2,3,3};
  int p = blockIdx.x;
  int R = RA[p], C = CA[p];
  bool diag = (R == C);
  int tid = threadIdx.x;
  int r = tid >> 2, c0 = (tid & 3) * 16;

  const us8* sa = (const us8*)(pl + (size_t)(R * 64 + r) * 256 + C * 64 + c0);
  us8 a0 = sa[0], a1 = sa[1];
  #pragma unroll
  for (int s = 0; s < 8; ++s) { ta[r][c0 + s] = a0[s]; ta[r][c0 + 8 + s] = a1[s]; }
  if (!diag) {
    const us8* sb = (const us8*)(pl + (size_t)(C * 64 + r) * 256 + R * 64 + c0);
    us8 b0 = sb[0], b1 = sb[1];
    #pragma unroll
    for (int s = 0; s < 8; ++s) { tb[r][c0 + s] = b0[s]; tb[r][c0 + 8 + s] = b1[s]; }
  }
  __syncthreads();
  us8 o0, o1;
  #pragma unroll
  for (int s = 0; s < 8; ++s) { o0[s] = ta[c0 + s][r]; o1[s] = ta[c0 + 8 + s][r]; }
  us8* da = (us8*)(pl + (size_t)(C * 64 + r) * 256 + R * 64 + c0);
  da[0] = o0; da[1] = o1;
  if (!diag) {
    us8 p0, p1;
    #pragma unroll
    for (int s = 0; s < 8; ++s) { p0[s] = tb[c0 + s][r]; p1[s] = tb[c0 + 8 + s][r]; }
    us8* db = (us8*)(pl + (size_t)(R * 64 + r) * 256 + C * 64 + c0);
    db[0] = p0; db[1] = p1;
  }
}

// ---------- row softmax over 256 fp32 -> bf16 P; one wave per row ----------
__global__ void softmax_kernel(const float* __restrict__ S, u16* __restrict__ P) {
  int row = blockIdx.x * 4 + (threadIdx.x >> 6);
  int lane = threadIdx.x & 63;
  f32x4 v = ((const f32x4*)(S + (size_t)row * 256))[lane];
  float mx = fmaxf(fmaxf(v[0], v[1]), fmaxf(v[2], v[3]));
  #pragma unroll
  for (int o = 32; o > 0; o >>= 1) mx = fmaxf(mx, __shfl_xor(mx, o));
  float e0 = __expf(v[0] - mx), e1 = __expf(v[1] - mx);
  float e2 = __expf(v[2] - mx), e3 = __expf(v[3] - mx);
  float sum = e0 + e1 + e2 + e3;
  #pragma unroll
  for (int o = 32; o > 0; o >>= 1) sum += __shfl_xor(sum, o);
  float inv = 1.0f / sum;
  ushort4 p;
  p.x = f2bf(e0 * inv); p.y = f2bf(e1 * inv); p.z = f2bf(e2 * inv); p.w = f2bf(e3 * inv);
  ((ushort4*)(P + (size_t)row * 256))[lane] = p;
}

extern "C" void kernel_launch(void* const* d_in, const int* in_sizes, int n_in,
                              void* d_out, int out_size, void* d_ws, size_t ws_size,
                              hipStream_t stream) {
  const float* x  = (const float*)d_in[0];   // [16384, 2048]
  const float* wq = (const float*)d_in[1];   // [6144, 2048]
  const float* wp = (const float*)d_in[2];   // [2048, 2048]
  const float* bp = (const float*)d_in[3];   // [2048]
  float* out = (float*)d_out;
  char* ws = (char*)d_ws;

  const size_t MB = 1ull << 20;
  const size_t NEED = 432 * MB;
  if (ws_size < NEED) {
    beacon_kernel<<<2048, 256, 0, stream>>>(out, (float)(ws_size >> 20), 16384 * 2048);
    return;
  }

  u16* q_hi = (u16*)(ws);
  u16* q_lo = (u16*)(ws + 64 * MB);
  u16* k_hi = (u16*)(ws + 128 * MB);
  u16* k_lo = (u16*)(ws + 192 * MB);
  u16* vbuf = (u16*)(ws + 256 * MB);
  u16* x_hi = (u16*)(ws + 320 * MB);
  u16* w_hi = (u16*)(ws + 384 * MB);
  u16* w_lo = (u16*)(ws + 408 * MB);
  float* S  = (float*)(ws + 320 * MB);
  u16* Pm   = (u16*)(ws + 352 * MB);
  u16* attn = (u16*)(ws + 368 * MB);
  u16* wpb  = (u16*)(ws + 320 * MB);

  split_kernel<<<8192, 256, 0, stream>>>(x,  x_hi, nullptr, 16384 * 2048 / 4);
  split_kernel<<<4096, 256, 0, stream>>>(wq, w_hi, w_lo, 6144 * 2048 / 4);

  // G1 qk: q,k = x_hi @ (w_hi | w_lo)^T  (2 K-segments of 32 BK=64 tiles)
  gemm256<0><<<1024, 512, 131072, stream>>>(
      x_hi, x_hi, w_hi, w_lo, 2048, 2048, 64, 5, 64,
      q_hi, q_lo, k_hi, k_lo, nullptr, nullptr, nullptr);
  // G1 v: v = x_hi @ wv_hi^T  (1 segment, 32 tiles)
  const u16* wv = w_hi + (size_t)4096 * 2048;
  gemm256<1><<<512, 512, 131072, stream>>>(
      x_hi, x_hi, wv, wv, 2048, 2048, 32, 5, 64,
      nullptr, nullptr, nullptr, nullptr, vbuf, nullptr, nullptr);

  transpose_inplace<<<dim3(10, 512, 3), 256, 0, stream>>>(k_hi, k_lo, vbuf);

  for (int gp = 0; gp < 4; ++gp) {
    int pb = gp * 128;
    gemm_nt<2, 0><<<dim3(2, 2, 128), 256, 0, stream>>>(
        k_hi, k_hi, k_lo, q_hi, q_lo, q_hi,
        S, nullptr, 24, 3, pb);
    softmax_kernel<<<8192, 256, 0, stream>>>(S, Pm);
    gemm_nt<3, 0><<<dim3(2, 2, 128), 256, 0, stream>>>(
        Pm, Pm, Pm, vbuf, vbuf, vbuf,
        nullptr, attn, 8, 3, pb);
  }

  split_kernel<<<2048, 256, 0, stream>>>(wp, wpb, nullptr, 2048 * 2048 / 4);
  gemm256<2><<<512, 512, 131072, stream>>>(
      attn, attn, wpb, wpb, 2048, 2048, 32, 5, 64,
      nullptr, nullptr, nullptr, nullptr, nullptr, out, bp);
}

// Round 9
// 1093.211 us; speedup vs baseline: 1.0789x; 1.0479x over previous
//
#include <hip/hip_runtime.h>
#include <hip/hip_bf16.h>

typedef unsigned short u16;
typedef __attribute__((ext_vector_type(4))) float f32x4;
typedef __attribute__((ext_vector_type(8))) short short8;
typedef __attribute__((ext_vector_type(8))) u16 us8;

// Geometry (fixed): B=64, N=256, DIM=2048, H=8, D=256; M=B*N=16384; qkvN=6144

__device__ __forceinline__ u16 f2bf(float f) {
  union { float f; unsigned u; } v; v.f = f;
  unsigned r = v.u + 0x7fffu + ((v.u >> 16) & 1u);   // RNE, finite inputs
  return (u16)(r >> 16);
}
__device__ __forceinline__ float bf2f(u16 h) {
  union { unsigned u; float f; } v; v.u = ((unsigned)h) << 16; return v.f;
}

__global__ void beacon_kernel(float* __restrict__ out, float val, int n) {
  int stride = gridDim.x * blockDim.x;
  for (int i = blockIdx.x * blockDim.x + threadIdx.x; i < n; i += stride)
    out[i] = val;
}

__global__ void split_kernel(const float* __restrict__ in, u16* __restrict__ hi,
                             u16* __restrict__ lo, int n4) {
  int stride = gridDim.x * blockDim.x;
  for (int i = blockIdx.x * blockDim.x + threadIdx.x; i < n4; i += stride) {
    f32x4 v = ((const f32x4*)in)[i];
    ushort4 h;
    h.x = f2bf(v[0]); h.y = f2bf(v[1]); h.z = f2bf(v[2]); h.w = f2bf(v[3]);
    ((ushort4*)hi)[i] = h;
    if (lo) {
      ushort4 l;
      l.x = f2bf(v[0] - bf2f(h.x)); l.y = f2bf(v[1] - bf2f(h.y));
      l.z = f2bf(v[2] - bf2f(h.z)); l.w = f2bf(v[3] - bf2f(h.w));
      ((ushort4*)lo)[i] = l;
    }
  }
}

#define SCHED0 __builtin_amdgcn_sched_barrier(0)
#define LGKM0 do { asm volatile("s_waitcnt lgkmcnt(0)" ::: "memory"); SCHED0; } while (0)
#define VM0 do { asm volatile("s_waitcnt vmcnt(0)" ::: "memory"); } while (0)
#define BAR __builtin_amdgcn_s_barrier()

// ====== 256x256 4-phase bf16 NT GEMM (round-6 version, HW-validated 527us) ======
// C[M,N] = A[M,K']*B[N,K']^T; K' = up to 2 concatenated segments; BK=64.
// All 8 stage-loads of tile t+1 issued at P1/P2 of tile t, drained by ONE
// vmcnt(0) before the P4-end barrier.  LDS [256][64] per operand, 2 dbuf.
// Slot swizzle phys = nat ^ (row&7) on read; source col pre-swizzled (rule 21).
// EPI 0: qkv->q,k scatter (hi+lo); EPI 1: qkv->v plane; EPI 2: proj out+bias.
template<int EPI>
__global__ __launch_bounds__(512, 2)
void gemm256(const u16* __restrict__ A0, const u16* __restrict__ A1,
             const u16* __restrict__ B0, const u16* __restrict__ B1,
             int ldA, int ldB, int ntiles, int segShift, int gridMx,
             u16* __restrict__ qh, u16* __restrict__ ql,
             u16* __restrict__ kh, u16* __restrict__ kl,
             u16* __restrict__ vv,
             float* __restrict__ fout, const float* __restrict__ bias) {
  extern __shared__ __align__(16) u16 lds[];   // 128 KiB: 2 dbuf x (A+B)[256][64]

  const int tid = threadIdx.x;
  const int w = tid >> 6, lane = tid & 63;
  const int wr = w >> 2, wcn = w & 3;          // 2M x 4N waves, 128x64 out each
  const int l15 = lane & 15, g = lane >> 4;
  const int rsw = l15 & 7;                     // read-side slot XOR (row&7)
  const int scol = (((tid & 7) ^ ((tid >> 3) & 7)) << 3);  // pre-swz src col

  int bid = blockIdx.x, cpx = gridDim.x >> 3;
  int swz = (bid & 7) * cpx + (bid >> 3);
  int m0 = (swz % gridMx) << 8;
  int n0 = (swz / gridMx) << 8;

  const u16* As[2] = {A0, A1};
  const u16* Bs[2] = {B0, B1};
  const int kmask = (1 << segShift) - 1;

  f32x4 acc[8][4] = {};
  short8 af[8], bA[4], bB[4];

  auto stageA = [&](int db, const u16* Ab, int k0) {
    #pragma unroll
    for (int s = 0; s < 4; ++s) {
      const u16* src = Ab + (size_t)(m0 + s * 64 + (tid >> 3)) * ldA + k0 + scol;
      u16* dst = lds + db * 32768 + s * 4096 + tid * 8;
      __builtin_amdgcn_global_load_lds(
          (const __attribute__((address_space(1))) unsigned*)src,
          (__attribute__((address_space(3))) unsigned*)dst, 16, 0, 0);
    }
  };
  auto stageB = [&](int db, const u16* Bb, int k0) {
    #pragma unroll
    for (int s = 0; s < 4; ++s) {
      const u16* src = Bb + (size_t)(n0 + s * 64 + (tid >> 3)) * ldB + k0 + scol;
      u16* dst = lds + db * 32768 + 16384 + s * 4096 + tid * 8;
      __builtin_amdgcn_global_load_lds(
          (const __attribute__((address_space(1))) unsigned*)src,
          (__attribute__((address_space(3))) unsigned*)dst, 16, 0, 0);
    }
  };
  auto readA = [&](int db, int MH) {
    #pragma unroll
    for (int f = 0; f < 4; ++f) {
      int row = wr * 128 + MH * 64 + f * 16 + l15;
      #pragma unroll
      for (int kk = 0; kk < 2; ++kk) {
        int sl = (kk * 4 + g) ^ rsw;
        af[f * 2 + kk] = *(const short8*)(lds + db * 32768 + row * 64 + sl * 8);
      }
    }
  };
  auto readB = [&](short8* bf, int db, int NH) {
    #pragma unroll
    for (int f = 0; f < 2; ++f) {
      int row = wcn * 64 + NH * 32 + f * 16 + l15;
      #pragma unroll
      for (int kk = 0; kk < 2; ++kk) {
        int sl = (kk * 4 + g) ^ rsw;
        bf[f * 2 + kk] = *(const short8*)(lds + db * 32768 + 16384 + row * 64 + sl * 8);
      }
    }
  };

#define MMA_QUAD(MH, NH, BF)                                                   \
  __builtin_amdgcn_s_setprio(1);                                               \
  _Pragma("unroll") for (int f = 0; f < 4; ++f)                                \
    _Pragma("unroll") for (int j = 0; j < 2; ++j)                              \
      _Pragma("unroll") for (int kk = 0; kk < 2; ++kk)                         \
        acc[(MH) * 4 + f][(NH) * 2 + j] =                                      \
            __builtin_amdgcn_mfma_f32_16x16x32_bf16(                           \
                af[f * 2 + kk], BF[j * 2 + kk],                                \
                acc[(MH) * 4 + f][(NH) * 2 + j], 0, 0, 0);                     \
  __builtin_amdgcn_s_setprio(0)

  const int T = ntiles;
  stageA(0, As[0], 0);
  stageB(0, Bs[0], 0);
  VM0;
  BAR; SCHED0;

  for (int t = 0; t < T - 1; ++t) {
    int cur = t & 1, nxt = cur ^ 1;
    int t1 = t + 1;
    const u16* An = As[t1 >> segShift];
    const u16* Bn = Bs[t1 >> segShift];
    int kn = (t1 & kmask) << 6;
    readA(cur, 0);
    readB(bA, cur, 0);
    stageA(nxt, An, kn);
    BAR; LGKM0;
    MMA_QUAD(0, 0, bA);
    BAR; SCHED0;
    readB(bB, cur, 1);
    stageB(nxt, Bn, kn);
    BAR; LGKM0;
    MMA_QUAD(0, 1, bB);
    BAR; SCHED0;
    readA(cur, 1);
    BAR; LGKM0;
    MMA_QUAD(1, 1, bB);
    BAR; SCHED0;
    MMA_QUAD(1, 0, bA);
    VM0;
    BAR; SCHED0;
  }
  {
    int cur = (T - 1) & 1;
    readA(cur, 0);
    readB(bA, cur, 0);
    LGKM0;
    MMA_QUAD(0, 0, bA);
    readB(bB, cur, 1);
    LGKM0;
    MMA_QUAD(0, 1, bB);
    readA(cur, 1);
    LGKM0;
    MMA_QUAD(1, 1, bB);
    MMA_QUAD(1, 0, bA);
  }
#undef MMA_QUAD

  #pragma unroll
  for (int i = 0; i < 8; ++i)
    #pragma unroll
    for (int j = 0; j < 4; ++j)
      #pragma unroll
      for (int rr = 0; rr < 4; ++rr) {
        int gm = m0 + wr * 128 + i * 16 + g * 4 + rr;
        int gn = n0 + wcn * 64 + j * 16 + l15;
        float val = acc[i][j][rr];
        if constexpr (EPI == 0) {
          int b = gm >> 8, tok = gm & 255;
          int sel = gn >> 11, head = (gn >> 8) & 7, col = gn & 255;
          size_t addr = (((size_t)b * 8 + head) * 256 + tok) * 256 + col;
          u16 h = f2bf(val), lo = f2bf(val - bf2f(h));
          if (sel == 0) { qh[addr] = h; ql[addr] = lo; }
          else          { kh[addr] = h; kl[addr] = lo; }
        } else if constexpr (EPI == 1) {
          int b = gm >> 8, tok = gm & 255;
          int head = (gn >> 8) & 7, col = gn & 255;
          size_t addr = (((size_t)b * 8 + head) * 256 + tok) * 256 + col;
          vv[addr] = f2bf(val);
        } else {
          fout[(size_t)gm * 2048 + gn] = val + bias[gn];
        }
      }
}

// ====== fused logits+softmax: P[plane][i][j] = softmax_j( kT*q^T ) ======
// Block (mtile, plane): 4 waves; wave w owns rows w*32..+31 (of block's 128),
// ALL 256 cols -> softmax row lives in one wave.  K' = 768 (k_hi*q_hi |
// k_hi*q_lo | k_lo*q_hi), same accumulation order as the old G2 -> S
// bit-identical; softmax in-register (max order-independent; sum reorder
// ~2^-24 relative).  Staging/swizzle constants identical to validated gemm_nt.
__global__ __launch_bounds__(256)
void attn_fused(const u16* __restrict__ kh, const u16* __restrict__ kl,
                const u16* __restrict__ qh, const u16* __restrict__ ql,
                u16* __restrict__ P) {
  __shared__ __align__(16) u16 sA[4096];   // 128x32
  __shared__ __align__(16) u16 sB[8192];   // 256x32
  const int tid = threadIdx.x;
  const int wave = tid >> 6, lane = tid & 63;
  const int l15 = lane & 15, l16 = lane >> 4;
  const int sxor = (l15 >> 1) & 3;
  const int scol = ((lane & 3) ^ ((lane >> 3) & 3)) * 8;
  const int m0 = blockIdx.x << 7;
  const size_t zo = (size_t)blockIdx.y * 65536;
  const u16* As[3] = {kh + zo, kh + zo, kl + zo};
  const u16* Bs[3] = {qh + zo, ql + zo, qh + zo};

  f32x4 acc[2][16] = {};

  for (int ks = 0; ks < 24; ++ks) {
    int seg = ks >> 3, k0 = (ks & 7) * 32;
    {  // stage A 128x32 (2 loads/thread)
      const u16* gp = As[seg];
      #pragma unroll
      for (int c = 0; c < 2; ++c) {
        int chunk = wave + c * 4;
        int r = chunk * 16 + (lane >> 2);
        const u16* src = gp + (size_t)(m0 + r) * 256 + k0 + scol;
        __builtin_amdgcn_global_load_lds(
            (const __attribute__((address_space(1))) unsigned*)src,
            (__attribute__((address_space(3))) unsigned*)(sA + chunk * 512), 16, 0, 0);
      }
    }
    {  // stage B 256x32 (4 loads/thread)
      const u16* gp = Bs[seg];
      #pragma unroll
      for (int c = 0; c < 4; ++c) {
        int chunk = wave + c * 4;
        int r = chunk * 16 + (lane >> 2);
        const u16* src = gp + (size_t)r * 256 + k0 + scol;
        __builtin_amdgcn_global_load_lds(
            (const __attribute__((address_space(1))) unsigned*)src,
            (__attribute__((address_space(3))) unsigned*)(sB + chunk * 512), 16, 0, 0);
      }
    }
    __syncthreads();

    short8 a[2];
    #pragma unroll
    for (int i = 0; i < 2; ++i) {
      int ra = (wave * 32 + i * 16 + l15) * 4 + (l16 ^ sxor);
      a[i] = ((const short8*)sA)[ra];
    }
    #pragma unroll
    for (int h = 0; h < 2; ++h) {
      short8 b[8];
      #pragma unroll
      for (int c = 0; c < 8; ++c) {
        int rb = ((h * 8 + c) * 16 + l15) * 4 + (l16 ^ sxor);
        b[c] = ((const short8*)sB)[rb];
      }
      #pragma unroll
      for (int i = 0; i < 2; ++i)
        #pragma unroll
        for (int c = 0; c < 8; ++c)
          acc[i][h * 8 + c] = __builtin_amdgcn_mfma_f32_16x16x32_bf16(
              a[i], b[c], acc[i][h * 8 + c], 0, 0, 0);
    }
    __syncthreads();
  }

  // per-row softmax over 256 cols; row = m0 + wave*32 + i*16 + l16*4 + rr,
  // held by the 16 lanes sharing l16 (cols l15 + 16c).
  u16* Pp = P + zo;
  #pragma unroll
  for (int i = 0; i < 2; ++i)
    #pragma unroll
    for (int rr = 0; rr < 4; ++rr) {
      float m = acc[i][0][rr];
      #pragma unroll
      for (int c = 1; c < 16; ++c) m = fmaxf(m, acc[i][c][rr]);
      #pragma unroll
      for (int sh = 1; sh < 16; sh <<= 1) m = fmaxf(m, __shfl_xor(m, sh));
      float e[16];
      float s = 0.f;
      #pragma unroll
      for (int c = 0; c < 16; ++c) { e[c] = __expf(acc[i][c][rr] - m); s += e[c]; }
      #pragma unroll
      for (int sh = 1; sh < 16; sh <<= 1) s += __shfl_xor(s, sh);
      float inv = 1.0f / s;
      int row = m0 + wave * 32 + i * 16 + l16 * 4 + rr;
      #pragma unroll
      for (int c = 0; c < 16; ++c)
        Pp[(size_t)row * 256 + c * 16 + l15] = f2bf(e[c] * inv);
    }
}

// ============ plain bf16 NT GEMM (m97 structure, HW-validated) — G3 ============
template<int EPI>
__global__ __launch_bounds__(256)
void gemm_nt(const u16* __restrict__ A0, const u16* __restrict__ B0,
             u16* __restrict__ aout, int ksteps) {
  __shared__ __align__(16) u16 lds[8192];
  u16* sA = lds;
  u16* sB = lds + 4096;

  const int tid = threadIdx.x;
  const int wave = tid >> 6, lane = tid & 63;
  const int wr = wave >> 1, wc = wave & 1;
  const int l15 = lane & 15, l16 = lane >> 4;
  const int sxor = (l15 >> 1) & 3;

  size_t zoff = (size_t)blockIdx.z * 65536;
  const u16* Ab = A0 + zoff;
  const u16* Bb = B0 + zoff;

  const int m0 = blockIdx.x << 7;
  const int n0 = blockIdx.y << 7;

  f32x4 acc[4][4] = {};

  auto stage = [&](const u16* gp, u16* slot, int row0, int k0) {
    int scol = ((lane & 3) ^ ((lane >> 3) & 3)) * 8;
    #pragma unroll
    for (int c = 0; c < 2; ++c) {
      int chunk = wave + c * 4;
      int r = chunk * 16 + (lane >> 2);
      const u16* src = gp + (size_t)(row0 + r) * 256 + (k0 + scol);
      __builtin_amdgcn_global_load_lds(
          (const __attribute__((address_space(1))) unsigned*)src,
          (__attribute__((address_space(3))) unsigned*)(slot + chunk * 512), 16, 0, 0);
    }
  };

  for (int ks = 0; ks < ksteps; ++ks) {
    int k0 = ks * 32;
    stage(Ab, sA, m0, k0);
    stage(Bb, sB, n0, k0);
    __syncthreads();

    short8 a[4], b[4];
    #pragma unroll
    for (int i = 0; i < 4; ++i) {
      int ra = (wr * 64 + i * 16 + l15) * 4 + (l16 ^ sxor);
      int rb = (wc * 64 + i * 16 + l15) * 4 + (l16 ^ sxor);
      a[i] = ((const short8*)sA)[ra];
      b[i] = ((const short8*)sB)[rb];
    }
    #pragma unroll
    for (int i = 0; i < 4; ++i)
      #pragma unroll
      for (int j = 0; j < 4; ++j)
        acc[i][j] = __builtin_amdgcn_mfma_f32_16x16x32_bf16(a[i], b[j], acc[i][j], 0, 0, 0);
    __syncthreads();
  }

  #pragma unroll
  for (int i = 0; i < 4; ++i)
    #pragma unroll
    for (int j = 0; j < 4; ++j)
      #pragma unroll
      for (int r = 0; r < 4; ++r) {
        int gm = m0 + wr * 64 + i * 16 + l16 * 4 + r;
        int gn = n0 + wc * 64 + j * 16 + l15;
        int gp = blockIdx.z;
        size_t row = (size_t)(gp >> 3) * 256 + gm;
        size_t col = (size_t)(gp & 7) * 256 + gn;
        aout[row * 2048 + col] = f2bf(acc[i][j][r]);
      }
}

// ---------- per-head 256x256 in-place transpose (k_hi, k_lo, v) ----------
__global__ void transpose_inplace(u16* __restrict__ kh, u16* __restrict__ kl,
                                  u16* __restrict__ v) {
  __shared__ u16 ta[64][66], tb[64][66];
  u16* base = (blockIdx.z == 0) ? kh : (blockIdx.z == 1) ? kl : v;
  u16* pl = base + (size_t)blockIdx.y * 65536;
  const int RA[10] = {0,1,2,3, 0,0,0,1,1,2};
  const int CA[10] = {0,1,2,3, 1,2,3,2,3,3};
  int p = blockIdx.x;
  int R = RA[p], C = CA[p];
  bool diag = (R == C);
  int tid = threadIdx.x;
  int r = tid >> 2, c0 = (tid & 3) * 16;

  const us8* sa = (const us8*)(pl + (size_t)(R * 64 + r) * 256 + C * 64 + c0);
  us8 a0 = sa[0], a1 = sa[1];
  #pragma unroll
  for (int s = 0; s < 8; ++s) { ta[r][c0 + s] = a0[s]; ta[r][c0 + 8 + s] = a1[s]; }
  if (!diag) {
    const us8* sb = (const us8*)(pl + (size_t)(C * 64 + r) * 256 + R * 64 + c0);
    us8 b0 = sb[0], b1 = sb[1];
    #pragma unroll
    for (int s = 0; s < 8; ++s) { tb[r][c0 + s] = b0[s]; tb[r][c0 + 8 + s] = b1[s]; }
  }
  __syncthreads();
  us8 o0, o1;
  #pragma unroll
  for (int s = 0; s < 8; ++s) { o0[s] = ta[c0 + s][r]; o1[s] = ta[c0 + 8 + s][r]; }
  us8* da = (us8*)(pl + (size_t)(C * 64 + r) * 256 + R * 64 + c0);
  da[0] = o0; da[1] = o1;
  if (!diag) {
    us8 p0, p1;
    #pragma unroll
    for (int s = 0; s < 8; ++s) { p0[s] = tb[c0 + s][r]; p1[s] = tb[c0 + 8 + s][r]; }
    us8* db = (us8*)(pl + (size_t)(R * 64 + r) * 256 + C * 64 + c0);
    db[0] = p0; db[1] = p1;
  }
}

extern "C" void kernel_launch(void* const* d_in, const int* in_sizes, int n_in,
                              void* d_out, int out_size, void* d_ws, size_t ws_size,
                              hipStream_t stream) {
  const float* x  = (const float*)d_in[0];   // [16384, 2048]
  const float* wq = (const float*)d_in[1];   // [6144, 2048]
  const float* wp = (const float*)d_in[2];   // [2048, 2048]
  const float* bp = (const float*)d_in[3];   // [2048]
  float* out = (float*)d_out;
  char* ws = (char*)d_ws;

  const size_t MB = 1ull << 20;
  const size_t NEED = 432 * MB;
  if (ws_size < NEED) {
    beacon_kernel<<<2048, 256, 0, stream>>>(out, (float)(ws_size >> 20), 16384 * 2048);
    return;
  }

  // persistent per-head tensors [0, 320 MiB)
  u16* q_hi = (u16*)(ws);
  u16* q_lo = (u16*)(ws + 64 * MB);
  u16* k_hi = (u16*)(ws + 128 * MB);
  u16* k_lo = (u16*)(ws + 192 * MB);
  u16* vbuf = (u16*)(ws + 256 * MB);
  // G1 phase window [320, 432 MiB)
  u16* x_hi = (u16*)(ws + 320 * MB);   // 64 MiB
  u16* w_hi = (u16*)(ws + 384 * MB);   // 24 MiB
  u16* w_lo = (u16*)(ws + 408 * MB);   // 24 MiB
  // attention phase (x, w dead after G1)
  u16* Pm   = (u16*)(ws + 320 * MB);   // 64 MiB (over dead x_hi)
  u16* attn = (u16*)(ws + 128 * MB);   // 64 MiB (over dead k_hi; k dead after attn_fused)
  u16* wpb  = (u16*)(ws + 384 * MB);   //  8 MiB (over dead w_hi)

  split_kernel<<<8192, 256, 0, stream>>>(x,  x_hi, nullptr, 16384 * 2048 / 4);
  split_kernel<<<4096, 256, 0, stream>>>(wq, w_hi, w_lo, 6144 * 2048 / 4);

  // G1 qk: q,k = x_hi @ (w_hi | w_lo)^T  (2 K-segments of 32 BK=64 tiles)
  gemm256<0><<<1024, 512, 131072, stream>>>(
      x_hi, x_hi, w_hi, w_lo, 2048, 2048, 64, 5, 64,
      q_hi, q_lo, k_hi, k_lo, nullptr, nullptr, nullptr);
  // G1 v: v = x_hi @ wv_hi^T  (1 segment, 32 tiles)
  const u16* wv = w_hi + (size_t)4096 * 2048;
  gemm256<1><<<512, 512, 131072, stream>>>(
      x_hi, x_hi, wv, wv, 2048, 2048, 32, 5, 64,
      nullptr, nullptr, nullptr, nullptr, vbuf, nullptr, nullptr);

  // in-place per-head transpose of k (hi,lo) and v
  transpose_inplace<<<dim3(10, 512, 3), 256, 0, stream>>>(k_hi, k_lo, vbuf);

  // fused logits+softmax over all 512 planes -> P (bf16)
  attn_fused<<<dim3(2, 512), 256, 0, stream>>>(k_hi, k_lo, q_hi, q_lo, Pm);

  // PV: attn = P @ vT^T, all 512 planes in one launch
  gemm_nt<3><<<dim3(2, 2, 512), 256, 0, stream>>>(Pm, vbuf, attn, 8);

  // proj: out = attn @ wp^T + bias
  split_kernel<<<2048, 256, 0, stream>>>(wp, wpb, nullptr, 2048 * 2048 / 4);
  gemm256<2><<<512, 512, 131072, stream>>>(
      attn, attn, wpb, wpb, 2048, 2048, 32, 5, 64,
      nullptr, nullptr, nullptr, nullptr, nullptr, out, bp);
}

// Round 10
// 1071.905 us; speedup vs baseline: 1.1003x; 1.0199x over previous
//
#include <hip/hip_runtime.h>
#include <hip/hip_bf16.h>

typedef unsigned short u16;
typedef __attribute__((ext_vector_type(4))) float f32x4;
typedef __attribute__((ext_vector_type(8))) short short8;
typedef __attribute__((ext_vector_type(8))) u16 us8;

// Geometry (fixed): B=64, N=256, DIM=2048, H=8, D=256; M=B*N=16384; qkvN=6144

__device__ __forceinline__ u16 f2bf(float f) {
  union { float f; unsigned u; } v; v.f = f;
  unsigned r = v.u + 0x7fffu + ((v.u >> 16) & 1u);   // RNE, finite inputs
  return (u16)(r >> 16);
}
__device__ __forceinline__ float bf2f(u16 h) {
  union { unsigned u; float f; } v; v.u = ((unsigned)h) << 16; return v.f;
}

__global__ void beacon_kernel(float* __restrict__ out, float val, int n) {
  int stride = gridDim.x * blockDim.x;
  for (int i = blockIdx.x * blockDim.x + threadIdx.x; i < n; i += stride)
    out[i] = val;
}

__global__ void split_kernel(const float* __restrict__ in, u16* __restrict__ hi,
                             u16* __restrict__ lo, int n4) {
  int stride = gridDim.x * blockDim.x;
  for (int i = blockIdx.x * blockDim.x + threadIdx.x; i < n4; i += stride) {
    f32x4 v = ((const f32x4*)in)[i];
    ushort4 h;
    h.x = f2bf(v[0]); h.y = f2bf(v[1]); h.z = f2bf(v[2]); h.w = f2bf(v[3]);
    ((ushort4*)hi)[i] = h;
    if (lo) {
      ushort4 l;
      l.x = f2bf(v[0] - bf2f(h.x)); l.y = f2bf(v[1] - bf2f(h.y));
      l.z = f2bf(v[2] - bf2f(h.z)); l.w = f2bf(v[3] - bf2f(h.w));
      ((ushort4*)lo)[i] = l;
    }
  }
}

#define SCHED0 __builtin_amdgcn_sched_barrier(0)
#define LGKM0 do { asm volatile("s_waitcnt lgkmcnt(0)" ::: "memory"); SCHED0; } while (0)
#define VM0 do { asm volatile("s_waitcnt vmcnt(0)" ::: "memory"); } while (0)
#define BAR __builtin_amdgcn_s_barrier()

// ====== 256x256 4-phase bf16 NT GEMM (round-6 version, HW-validated 527us) ======
template<int EPI>
__global__ __launch_bounds__(512, 2)
void gemm256(const u16* __restrict__ A0, const u16* __restrict__ A1,
             const u16* __restrict__ B0, const u16* __restrict__ B1,
             int ldA, int ldB, int ntiles, int segShift, int gridMx,
             u16* __restrict__ qh, u16* __restrict__ ql,
             u16* __restrict__ kh, u16* __restrict__ kl,
             u16* __restrict__ vv,
             float* __restrict__ fout, const float* __restrict__ bias) {
  extern __shared__ __align__(16) u16 lds[];   // 128 KiB: 2 dbuf x (A+B)[256][64]

  const int tid = threadIdx.x;
  const int w = tid >> 6, lane = tid & 63;
  const int wr = w >> 2, wcn = w & 3;          // 2M x 4N waves, 128x64 out each
  const int l15 = lane & 15, g = lane >> 4;
  const int rsw = l15 & 7;                     // read-side slot XOR (row&7)
  const int scol = (((tid & 7) ^ ((tid >> 3) & 7)) << 3);  // pre-swz src col

  int bid = blockIdx.x, cpx = gridDim.x >> 3;
  int swz = (bid & 7) * cpx + (bid >> 3);
  int m0 = (swz % gridMx) << 8;
  int n0 = (swz / gridMx) << 8;

  const u16* As[2] = {A0, A1};
  const u16* Bs[2] = {B0, B1};
  const int kmask = (1 << segShift) - 1;

  f32x4 acc[8][4] = {};
  short8 af[8], bA[4], bB[4];

  auto stageA = [&](int db, const u16* Ab, int k0) {
    #pragma unroll
    for (int s = 0; s < 4; ++s) {
      const u16* src = Ab + (size_t)(m0 + s * 64 + (tid >> 3)) * ldA + k0 + scol;
      u16* dst = lds + db * 32768 + s * 4096 + tid * 8;
      __builtin_amdgcn_global_load_lds(
          (const __attribute__((address_space(1))) unsigned*)src,
          (__attribute__((address_space(3))) unsigned*)dst, 16, 0, 0);
    }
  };
  auto stageB = [&](int db, const u16* Bb, int k0) {
    #pragma unroll
    for (int s = 0; s < 4; ++s) {
      const u16* src = Bb + (size_t)(n0 + s * 64 + (tid >> 3)) * ldB + k0 + scol;
      u16* dst = lds + db * 32768 + 16384 + s * 4096 + tid * 8;
      __builtin_amdgcn_global_load_lds(
          (const __attribute__((address_space(1))) unsigned*)src,
          (__attribute__((address_space(3))) unsigned*)dst, 16, 0, 0);
    }
  };
  auto readA = [&](int db, int MH) {
    #pragma unroll
    for (int f = 0; f < 4; ++f) {
      int row = wr * 128 + MH * 64 + f * 16 + l15;
      #pragma unroll
      for (int kk = 0; kk < 2; ++kk) {
        int sl = (kk * 4 + g) ^ rsw;
        af[f * 2 + kk] = *(const short8*)(lds + db * 32768 + row * 64 + sl * 8);
      }
    }
  };
  auto readB = [&](short8* bf, int db, int NH) {
    #pragma unroll
    for (int f = 0; f < 2; ++f) {
      int row = wcn * 64 + NH * 32 + f * 16 + l15;
      #pragma unroll
      for (int kk = 0; kk < 2; ++kk) {
        int sl = (kk * 4 + g) ^ rsw;
        bf[f * 2 + kk] = *(const short8*)(lds + db * 32768 + 16384 + row * 64 + sl * 8);
      }
    }
  };

#define MMA_QUAD(MH, NH, BF)                                                   \
  __builtin_amdgcn_s_setprio(1);                                               \
  _Pragma("unroll") for (int f = 0; f < 4; ++f)                                \
    _Pragma("unroll") for (int j = 0; j < 2; ++j)                              \
      _Pragma("unroll") for (int kk = 0; kk < 2; ++kk)                         \
        acc[(MH) * 4 + f][(NH) * 2 + j] =                                      \
            __builtin_amdgcn_mfma_f32_16x16x32_bf16(                           \
                af[f * 2 + kk], BF[j * 2 + kk],                                \
                acc[(MH) * 4 + f][(NH) * 2 + j], 0, 0, 0);                     \
  __builtin_amdgcn_s_setprio(0)

  const int T = ntiles;
  stageA(0, As[0], 0);
  stageB(0, Bs[0], 0);
  VM0;
  BAR; SCHED0;

  for (int t = 0; t < T - 1; ++t) {
    int cur = t & 1, nxt = cur ^ 1;
    int t1 = t + 1;
    const u16* An = As[t1 >> segShift];
    const u16* Bn = Bs[t1 >> segShift];
    int kn = (t1 & kmask) << 6;
    readA(cur, 0);
    readB(bA, cur, 0);
    stageA(nxt, An, kn);
    BAR; LGKM0;
    MMA_QUAD(0, 0, bA);
    BAR; SCHED0;
    readB(bB, cur, 1);
    stageB(nxt, Bn, kn);
    BAR; LGKM0;
    MMA_QUAD(0, 1, bB);
    BAR; SCHED0;
    readA(cur, 1);
    BAR; LGKM0;
    MMA_QUAD(1, 1, bB);
    BAR; SCHED0;
    MMA_QUAD(1, 0, bA);
    VM0;
    BAR; SCHED0;
  }
  {
    int cur = (T - 1) & 1;
    readA(cur, 0);
    readB(bA, cur, 0);
    LGKM0;
    MMA_QUAD(0, 0, bA);
    readB(bB, cur, 1);
    LGKM0;
    MMA_QUAD(0, 1, bB);
    readA(cur, 1);
    LGKM0;
    MMA_QUAD(1, 1, bB);
    MMA_QUAD(1, 0, bA);
  }
#undef MMA_QUAD

  #pragma unroll
  for (int i = 0; i < 8; ++i)
    #pragma unroll
    for (int j = 0; j < 4; ++j)
      #pragma unroll
      for (int rr = 0; rr < 4; ++rr) {
        int gm = m0 + wr * 128 + i * 16 + g * 4 + rr;
        int gn = n0 + wcn * 64 + j * 16 + l15;
        float val = acc[i][j][rr];
        if constexpr (EPI == 0) {
          int b = gm >> 8, tok = gm & 255;
          int sel = gn >> 11, head = (gn >> 8) & 7, col = gn & 255;
          size_t addr = (((size_t)b * 8 + head) * 256 + tok) * 256 + col;
          u16 h = f2bf(val), lo = f2bf(val - bf2f(h));
          if (sel == 0) { qh[addr] = h; ql[addr] = lo; }
          else          { kh[addr] = h; kl[addr] = lo; }
        } else if constexpr (EPI == 1) {
          int b = gm >> 8, tok = gm & 255;
          int head = (gn >> 8) & 7, col = gn & 255;
          size_t addr = (((size_t)b * 8 + head) * 256 + tok) * 256 + col;
          vv[addr] = f2bf(val);
        } else {
          fout[(size_t)gm * 2048 + gn] = val + bias[gn];
        }
      }
}

// ====== fully fused attention: logits (3-seg compensated) + softmax + PV ======
// Block (mtile 0..3, plane 0..511): 64 P-rows; 4 waves x 16 rows.
// Phase L: S^T rows = kT*q^T over K'=768 (kh*qh | kh*ql | kl*qh), identical
//   order to round-9 attn_fused -> S bit-identical.  Softmax in-register.
// P -> LDS [64][276] bf16 (pad 276: write banks 8*l16+(l15>>1) disjoint;
//   read stride 552B -> 10*l15 mod 32, 16 distinct banks).
// Phase PV: attn rows = P(64x256) x vT^T, vT staged with the validated
//   8/16-chunk pattern; MFMA shape/order identical to old gemm_nt<3> ->
//   PV bit-identical.  Epilogue scatters to attn[b*256+i][h*256+d].
__global__ __launch_bounds__(256)
void fused_attn(const u16* __restrict__ kh, const u16* __restrict__ kl,
                const u16* __restrict__ qh, const u16* __restrict__ ql,
                const u16* __restrict__ vT, u16* __restrict__ aout) {
  __shared__ __align__(16) u16 sA[2048];          // 64x32
  __shared__ __align__(16) u16 sB[8192];          // 256x32 (q / vT staging)
  __shared__ __align__(16) u16 sP[64 * 276];      // P, padded

  const int tid = threadIdx.x;
  const int wave = tid >> 6, lane = tid & 63;
  const int l15 = lane & 15, l16 = lane >> 4;
  const int sxor = (l15 >> 1) & 3;
  const int scol = ((lane & 3) ^ ((lane >> 3) & 3)) * 8;
  const int m0 = blockIdx.x << 6;                  // 64-row tile
  const size_t zo = (size_t)blockIdx.y * 65536;
  const u16* As[3] = {kh + zo, kh + zo, kl + zo};
  const u16* Bs[3] = {qh + zo, ql + zo, qh + zo};

  // ---- phase L: logits ----
  f32x4 acc[16] = {};
  for (int ks = 0; ks < 24; ++ks) {
    int seg = ks >> 3, k0 = (ks & 7) * 32;
    {  // stage A 64x32 (1 load/thread, 4 chunks of 16 rows)
      const u16* gp = As[seg];
      int chunk = wave;
      int r = chunk * 16 + (lane >> 2);
      const u16* src = gp + (size_t)(m0 + r) * 256 + k0 + scol;
      __builtin_amdgcn_global_load_lds(
          (const __attribute__((address_space(1))) unsigned*)src,
          (__attribute__((address_space(3))) unsigned*)(sA + chunk * 512), 16, 0, 0);
    }
    {  // stage B 256x32 (4 loads/thread, 16 chunks)
      const u16* gp = Bs[seg];
      #pragma unroll
      for (int c = 0; c < 4; ++c) {
        int chunk = wave + c * 4;
        int r = chunk * 16 + (lane >> 2);
        const u16* src = gp + (size_t)r * 256 + k0 + scol;
        __builtin_amdgcn_global_load_lds(
            (const __attribute__((address_space(1))) unsigned*)src,
            (__attribute__((address_space(3))) unsigned*)(sB + chunk * 512), 16, 0, 0);
      }
    }
    __syncthreads();

    short8 a;
    {
      int ra = (wave * 16 + l15) * 4 + (l16 ^ sxor);
      a = ((const short8*)sA)[ra];
    }
    #pragma unroll
    for (int c = 0; c < 16; ++c) {
      int rb = (c * 16 + l15) * 4 + (l16 ^ sxor);
      short8 b = ((const short8*)sB)[rb];
      acc[c] = __builtin_amdgcn_mfma_f32_16x16x32_bf16(a, b, acc[c], 0, 0, 0);
    }
    __syncthreads();
  }

  // ---- softmax + P -> LDS ----
  #pragma unroll
  for (int rr = 0; rr < 4; ++rr) {
    float m = acc[0][rr];
    #pragma unroll
    for (int c = 1; c < 16; ++c) m = fmaxf(m, acc[c][rr]);
    #pragma unroll
    for (int sh = 1; sh < 16; sh <<= 1) m = fmaxf(m, __shfl_xor(m, sh));
    float e[16];
    float s = 0.f;
    #pragma unroll
    for (int c = 0; c < 16; ++c) { e[c] = __expf(acc[c][rr] - m); s += e[c]; }
    #pragma unroll
    for (int sh = 1; sh < 16; sh <<= 1) s += __shfl_xor(s, sh);
    float inv = 1.0f / s;
    int prow = wave * 16 + l16 * 4 + rr;           // row within block
    #pragma unroll
    for (int c = 0; c < 16; ++c)
      sP[prow * 276 + c * 16 + l15] = f2bf(e[c] * inv);
  }
  __syncthreads();   // P complete (per-wave lgkm drained by barrier semantics)

  // ---- phase PV: attn = P @ vT^T ----
  const int wr2 = wave >> 1, wc2 = wave & 1;       // 2x2: 32 rows x 128 cols
  f32x4 acc2[2][8] = {};
  for (int ks = 0; ks < 8; ++ks) {
    int k0 = ks * 32;
    {  // stage vT 256x32 into sB
      #pragma unroll
      for (int c = 0; c < 4; ++c) {
        int chunk = wave + c * 4;
        int r = chunk * 16 + (lane >> 2);
        const u16* src = vT + zo + (size_t)r * 256 + k0 + scol;
        __builtin_amdgcn_global_load_lds(
            (const __attribute__((address_space(1))) unsigned*)src,
            (__attribute__((address_space(3))) unsigned*)(sB + chunk * 512), 16, 0, 0);
      }
    }
    __syncthreads();

    short8 a[2], b[8];
    #pragma unroll
    for (int i = 0; i < 2; ++i) {
      int prow = wr2 * 32 + i * 16 + l15;
      a[i] = *(const short8*)(sP + prow * 276 + k0 + l16 * 8);
    }
    #pragma unroll
    for (int j = 0; j < 8; ++j) {
      int rb = ((wc2 * 128 + j * 16 + l15)) * 4 + (l16 ^ sxor);
      b[j] = ((const short8*)sB)[rb];
    }
    #pragma unroll
    for (int i = 0; i < 2; ++i)
      #pragma unroll
      for (int j = 0; j < 8; ++j)
        acc2[i][j] = __builtin_amdgcn_mfma_f32_16x16x32_bf16(a[i], b[j], acc2[i][j], 0, 0, 0);
    __syncthreads();
  }

  // epilogue: attn[(b*256+i)][(h*256+d)]
  int plane = blockIdx.y;
  #pragma unroll
  for (int i = 0; i < 2; ++i)
    #pragma unroll
    for (int j = 0; j < 8; ++j)
      #pragma unroll
      for (int rr = 0; rr < 4; ++rr) {
        int gi = m0 + wr2 * 32 + i * 16 + l16 * 4 + rr;
        int gd = wc2 * 128 + j * 16 + l15;
        size_t row = (size_t)(plane >> 3) * 256 + gi;
        size_t col = (size_t)(plane & 7) * 256 + gd;
        aout[row * 2048 + col] = f2bf(acc2[i][j][rr]);
      }
}

// ---------- per-head 256x256 in-place transpose (k_hi, k_lo, v) ----------
__global__ void transpose_inplace(u16* __restrict__ kh, u16* __restrict__ kl,
                                  u16* __restrict__ v) {
  __shared__ u16 ta[64][66], tb[64][66];
  u16* base = (blockIdx.z == 0) ? kh : (blockIdx.z == 1) ? kl : v;
  u16* pl = base + (size_t)blockIdx.y * 65536;
  const int RA[10] = {0,1,2,3, 0,0,0,1,1,2};
  const int CA[10] = {0,1,2,3, 1,2,3,2,3,3};
  int p = blockIdx.x;
  int R = RA[p], C = CA[p];
  bool diag = (R == C);
  int tid = threadIdx.x;
  int r = tid >> 2, c0 = (tid & 3) * 16;

  const us8* sa = (const us8*)(pl + (size_t)(R * 64 + r) * 256 + C * 64 + c0);
  us8 a0 = sa[0], a1 = sa[1];
  #pragma unroll
  for (int s = 0; s < 8; ++s) { ta[r][c0 + s] = a0[s]; ta[r][c0 + 8 + s] = a1[s]; }
  if (!diag) {
    const us8* sb = (const us8*)(pl + (size_t)(C * 64 + r) * 256 + R * 64 + c0);
    us8 b0 = sb[0], b1 = sb[1];
    #pragma unroll
    for (int s = 0; s < 8; ++s) { tb[r][c0 + s] = b0[s]; tb[r][c0 + 8 + s] = b1[s]; }
  }
  __syncthreads();
  us8 o0, o1;
  #pragma unroll
  for (int s = 0; s < 8; ++s) { o0[s] = ta[c0 + s][r]; o1[s] = ta[c0 + 8 + s][r]; }
  us8* da = (us8*)(pl + (size_t)(C * 64 + r) * 256 + R * 64 + c0);
  da[0] = o0; da[1] = o1;
  if (!diag) {
    us8 p0, p1;
    #pragma unroll
    for (int s = 0; s < 8; ++s) { p0[s] = tb[c0 + s][r]; p1[s] = tb[c0 + 8 + s][r]; }
    us8* db = (us8*)(pl + (size_t)(R * 64 + r) * 256 + C * 64 + c0);
    db[0] = p0; db[1] = p1;
  }
}

extern "C" void kernel_launch(void* const* d_in, const int* in_sizes, int n_in,
                              void* d_out, int out_size, void* d_ws, size_t ws_size,
                              hipStream_t stream) {
  const float* x  = (const float*)d_in[0];   // [16384, 2048]
  const float* wq = (const float*)d_in[1];   // [6144, 2048]
  const float* wp = (const float*)d_in[2];   // [2048, 2048]
  const float* bp = (const float*)d_in[3];   // [2048]
  float* out = (float*)d_out;
  char* ws = (char*)d_ws;

  const size_t MB = 1ull << 20;
  const size_t NEED = 432 * MB;
  if (ws_size < NEED) {
    beacon_kernel<<<2048, 256, 0, stream>>>(out, (float)(ws_size >> 20), 16384 * 2048);
    return;
  }

  // persistent per-head tensors [0, 320 MiB)
  u16* q_hi = (u16*)(ws);
  u16* q_lo = (u16*)(ws + 64 * MB);
  u16* k_hi = (u16*)(ws + 128 * MB);
  u16* k_lo = (u16*)(ws + 192 * MB);
  u16* vbuf = (u16*)(ws + 256 * MB);
  // G1 phase window [320, 432 MiB)
  u16* x_hi = (u16*)(ws + 320 * MB);   // 64 MiB
  u16* w_hi = (u16*)(ws + 384 * MB);   // 24 MiB
  u16* w_lo = (u16*)(ws + 408 * MB);   // 24 MiB
  // attention phase (x, w dead after G1)
  u16* attn = (u16*)(ws + 320 * MB);   // 64 MiB (over dead x_hi)
  u16* wpb  = (u16*)(ws + 384 * MB);   //  8 MiB (over dead w_hi)

  split_kernel<<<8192, 256, 0, stream>>>(x,  x_hi, nullptr, 16384 * 2048 / 4);
  split_kernel<<<4096, 256, 0, stream>>>(wq, w_hi, w_lo, 6144 * 2048 / 4);

  // G1 qk: q,k = x_hi @ (w_hi | w_lo)^T  (2 K-segments of 32 BK=64 tiles)
  gemm256<0><<<1024, 512, 131072, stream>>>(
      x_hi, x_hi, w_hi, w_lo, 2048, 2048, 64, 5, 64,
      q_hi, q_lo, k_hi, k_lo, nullptr, nullptr, nullptr);
  // G1 v: v = x_hi @ wv_hi^T  (1 segment, 32 tiles)
  const u16* wv = w_hi + (size_t)4096 * 2048;
  gemm256<1><<<512, 512, 131072, stream>>>(
      x_hi, x_hi, wv, wv, 2048, 2048, 32, 5, 64,
      nullptr, nullptr, nullptr, nullptr, vbuf, nullptr, nullptr);

  // in-place per-head transpose of k (hi,lo) and v
  transpose_inplace<<<dim3(10, 512, 3), 256, 0, stream>>>(k_hi, k_lo, vbuf);

  // fused logits + softmax + PV over all 512 planes -> attn
  fused_attn<<<dim3(4, 512), 256, 0, stream>>>(k_hi, k_lo, q_hi, q_lo, vbuf, attn);

  // proj: out = attn @ wp^T + bias
  split_kernel<<<2048, 256, 0, stream>>>(wp, wpb, nullptr, 2048 * 2048 / 4);
  gemm256<2><<<512, 512, 131072, stream>>>(
      attn, attn, wpb, wpb, 2048, 2048, 32, 5, 64,
      nullptr, nullptr, nullptr, nullptr, nullptr, out, bp);
}